// Round 17
// baseline (336.573 us; speedup 1.0000x reference)
//
#include <hip/hip_runtime.h>

typedef _Float16 h16;
typedef __attribute__((ext_vector_type(8))) _Float16 h16x8;
typedef __attribute__((ext_vector_type(4))) float f32x4;
typedef unsigned int u32;

#define BARRIER() __builtin_amdgcn_s_barrier()
#define VMCNT(n)  asm volatile("s_waitcnt vmcnt(" #n ")" ::: "memory")

// ------------- Kernel 1: fused aux = A fp32->fp16  +  2:4 int4 dequant -------
__global__ __launch_bounds__(256) void aux_kernel(const float* __restrict__ A,
    h16* __restrict__ Ah, int total8,
    const int* __restrict__ Bq, const int* __restrict__ meta,
    const float* __restrict__ s, h16* __restrict__ Wt,
    int K, int N, int chunksPerGroup, int nBlocksN) {
  const int bid = blockIdx.x;
  if (bid < 2048) {
    int stride = 2048 * 256;
    for (int i = bid * 256 + threadIdx.x; i < total8; i += stride) {
      const f32x4* p = (const f32x4*)(A + (size_t)i * 8);
      f32x4 v0 = p[0], v1 = p[1];
      h16x8 o;
      o[0] = (h16)v0[0]; o[1] = (h16)v0[1]; o[2] = (h16)v0[2]; o[3] = (h16)v0[3];
      o[4] = (h16)v1[0]; o[5] = (h16)v1[1]; o[6] = (h16)v1[2]; o[7] = (h16)v1[3];
      *(h16x8*)(Ah + (size_t)i * 8) = o;
    }
  } else {
    const int db = bid - 2048;
    const int n = (db % nBlocksN) * 256 + threadIdx.x;   // column of W
    const int chunk = db / nBlocksN;                     // 32 dense k rows
    u32 w0 = (u32)Bq[(size_t)(chunk * 2) * N + n];
    u32 w1 = (u32)Bq[(size_t)(chunk * 2 + 1) * N + n];
    float sc = s[(size_t)(chunk / chunksPerGroup) * N + n];
    h16 out[32];
#pragma unroll
    for (int gi = 0; gi < 8; ++gi) {
      int g = chunk * 8 + gi;
      int mm = meta[(size_t)g * N + n];
      u32 w = (gi < 4) ? w0 : w1;
      int j0 = (2 * gi) & 7;
      float d0 = (float)((int)((w >> (4 * j0)) & 0xFu) - 8) * sc;
      float d1 = (float)((int)((w >> (4 * j0 + 4)) & 0xFu) - 8) * sc;
      u32 enc = (0xED9C84u >> (4 * mm)) & 0xFu;
      int p0 = (int)(enc & 3u), p1 = (int)(enc >> 2);
#pragma unroll
      for (int p = 0; p < 4; ++p) {
        float v = (p == p0) ? d0 : ((p == p1) ? d1 : 0.0f);
        out[gi * 4 + p] = (h16)v;
      }
    }
    h16* dst = Wt + (size_t)n * K + chunk * 32;
    *(h16x8*)(dst + 0)  = *(h16x8*)(out + 0);
    *(h16x8*)(dst + 8)  = *(h16x8*)(out + 8);
    *(h16x8*)(dst + 16) = *(h16x8*)(out + 16);
    *(h16x8*)(dst + 24) = *(h16x8*)(out + 24);
  }
}

// ---------------- Kernel 2: GEMM, R14 + half-prefetch reg rotation ----------
// R14 geometry: 256x256 tile, BK=32, 1024 thr (16 waves 4Mx4N, 64x64/wave),
// 4-slot 128 KiB LDS, counted vmcnt, same swizzle. NEW: af0,af1,bf0,bf1 of
// tile T are PREFETCHED during iter T-1 (16 persistent VGPR); af2,af3,bf2,bf3
// read transiently at iter top. MFMAs ordered to kill prefetched operands
// early, then the SAME variables are refilled from tile T+1 mid-iteration:
//   group1 (n=0,1): pure-prefetched pairs first -> kills bf0,bf1 -> refill
//   group2a (m=0,1 x n=2,3): kills af0,af1 -> refill
//   group2b (m=2,3 x n=2,3): transients only
// Every MFMA's operands are ready >=8 MFMAs (or a full iter) before use ->
// per-wave ds_read latency off the critical path; dependency-free MFMA
// stream overlaps the block-wide LDS read window.
// Ledger: prologue stages 0,1,2, vmcnt(2) publishes tiles 0,1; iter T stages
// T+3, vmcnt(2) publishes T+2 (one earlier than R14 -> licenses the T+1
// prefetch reads). Tail: vmcnt(0) at T=NT-3; barrier skipped once T+2>=NT.
__global__ __launch_bounds__(1024, 4) void gemm_kernel(const h16* __restrict__ A,
    const h16* __restrict__ Wt, const float* __restrict__ bias,
    float* __restrict__ C, int M, int N, int K) {
  __shared__ alignas(16) h16 As[4][8192];
  __shared__ alignas(16) h16 Bs[4][8192];

  const int nTilesN = N >> 8;
  const int nwg = gridDim.x;
  int bid = blockIdx.x;
  int wg = (bid & 7) * (nwg >> 3) + (bid >> 3);   // XCD swizzle (nwg%8==0)
  int tm = wg / nTilesN, tn = wg - tm * nTilesN;

  const int t = threadIdx.x;
  const int lane = t & 63, w = t >> 6;
  const int wr = w >> 2, wc = w & 3;

  // ---- staging: thread t covers LDS 16B-slot t; row=t>>2, dest col c=t&3
  // holds global chunk c ^ phi(row), phi(r) = (r>>1)&3 ----
  const int srow = t >> 2;
  const int chunk = (t & 3) ^ ((srow >> 1) & 3);
  const h16* gA_t = A + ((size_t)(tm * 256) + srow) * K + chunk * 8;
  const h16* gB_t = Wt + ((size_t)(tn * 256) + srow) * K + chunk * 8;
  const int t8 = t * 8;

#define GLOAD(SRC, DST) __builtin_amdgcn_global_load_lds(                      \
    (const __attribute__((address_space(1))) void*)(SRC),                      \
    (__attribute__((address_space(3))) void*)(DST), 16, 0, 0)

#define STAGE(T_) do {                                                         \
    GLOAD(gA_t + (size_t)(T_) * 32, &As[(T_) & 3][t8]);                        \
    GLOAD(gB_t + (size_t)(T_) * 32, &Bs[(T_) & 3][t8]);                        \
  } while (0)

  // ---- fragment read offsets: slot = l16 ^ phi(row) ----
  const int ln15 = lane & 15, l16 = lane >> 4;
  const int slA = (l16 ^ ((ln15 >> 1) & 3)) * 8;
  const int aBase = (wr * 64 + ln15) * 32 + slA;
  const int bBase = (wc * 64 + ln15) * 32 + slA;

#define MFMA1(M_, N_, AF_, BF_)                                                \
  acc[M_][N_] = __builtin_amdgcn_mfma_f32_16x16x32_f16(AF_, BF_, acc[M_][N_], 0, 0, 0)

  f32x4 acc[4][4] = {};
  const int NT = K >> 5;          // 128 for K=4096; assumed >= 4

  // prologue: stage tiles 0,1,2; publish 0,1; pre-read tile 0's frag half.
  STAGE(0); STAGE(1); STAGE(2);
  VMCNT(2);
  BARRIER();
  h16x8 pA0 = *(const h16x8*)(As[0] + aBase);
  h16x8 pA1 = *(const h16x8*)(As[0] + aBase + 512);
  h16x8 pB0 = *(const h16x8*)(Bs[0] + bBase);
  h16x8 pB1 = *(const h16x8*)(Bs[0] + bBase + 512);

  for (int T = 0; T < NT; ++T) {
    const h16* aS = As[T & 3];
    const h16* bS = Bs[T & 3];
    const h16* aSn = As[(T + 1) & 3];   // last iter reads stale slot; unused
    const h16* bSn = Bs[(T + 1) & 3];
    if (T + 3 < NT) STAGE(T + 3);
    // transient second halves of tile T
    h16x8 a2 = *(const h16x8*)(aS + aBase + 2 * 512);
    h16x8 a3 = *(const h16x8*)(aS + aBase + 3 * 512);
    h16x8 b2 = *(const h16x8*)(bS + bBase + 2 * 512);
    h16x8 b3 = *(const h16x8*)(bS + bBase + 3 * 512);
    // group 1 (n=0,1): pure-prefetched first; kills pB0,pB1
    MFMA1(0, 0, pA0, pB0); MFMA1(0, 1, pA0, pB1);
    MFMA1(1, 0, pA1, pB0); MFMA1(1, 1, pA1, pB1);
    MFMA1(2, 0, a2,  pB0); MFMA1(2, 1, a2,  pB1);
    MFMA1(3, 0, a3,  pB0); MFMA1(3, 1, a3,  pB1);
    // refill B prefetch from tile T+1 (consumers: next iteration)
    pB0 = *(const h16x8*)(bSn + bBase);
    pB1 = *(const h16x8*)(bSn + bBase + 512);
    // group 2a (m=0,1; n=2,3): kills pA0,pA1
    MFMA1(0, 2, pA0, b2); MFMA1(0, 3, pA0, b3);
    MFMA1(1, 2, pA1, b2); MFMA1(1, 3, pA1, b3);
    // refill A prefetch from tile T+1
    pA0 = *(const h16x8*)(aSn + aBase);
    pA1 = *(const h16x8*)(aSn + aBase + 512);
    // group 2b (m=2,3; n=2,3): transients only
    MFMA1(2, 2, a2, b2); MFMA1(2, 3, a2, b3);
    MFMA1(3, 2, a3, b2); MFMA1(3, 3, a3, b3);
    // counted publish: never drain while stages continue.
    if (T + 3 < NT) {
      VMCNT(2);
    } else if (T + 2 < NT) {
      VMCNT(0);
    }
    if (T + 2 < NT) BARRIER();
  }

  // ---- epilogue: col = ln15 (+n*16) from B side, row = l16*4+j (+m*16) ----
  int colBase = tn * 256 + wc * 64 + ln15;
  int rowBase = tm * 256 + wr * 64 + l16 * 4;
#pragma unroll
  for (int n = 0; n < 4; ++n) {
    float bv = bias[colBase + n * 16];
#pragma unroll
    for (int m = 0; m < 4; ++m) {
#pragma unroll
      for (int j = 0; j < 4; ++j) {
        C[(size_t)(rowBase + m * 16 + j) * N + colBase + n * 16] = acc[m][n][j] + bv;
      }
    }
  }
#undef MFMA1
#undef STAGE
#undef GLOAD
}

extern "C" void kernel_launch(void* const* d_in, const int* in_sizes, int n_in,
                              void* d_out, int out_size, void* d_ws, size_t ws_size,
                              hipStream_t stream) {
  const float* A = (const float*)d_in[0];
  const int* Bq = (const int*)d_in[1];
  const int* meta = (const int*)d_in[2];
  const float* s = (const float*)d_in[3];
  const float* bias = (const float*)d_in[4];
  float* C = (float*)d_out;

  const int N = in_sizes[4];
  const int K = (int)(((long long)in_sizes[1] * 16) / N);
  const int M = (int)((long long)in_sizes[0] / K);
  const int sRows = (int)((long long)in_sizes[3] / N);       // K/GS
  const int chunksPerGroup = (K / sRows) / 32;               // GS/32
  const int nBlocksN = N / 256;

  h16* Ah = (h16*)d_ws;                       // M*K f16 = 64 MiB
  h16* Wt = Ah + (size_t)M * K;               // N*K f16 = 32 MiB (W^T, K-major)

  int auxGrid = 2048 + nBlocksN * (K / 32);
  aux_kernel<<<auxGrid, 256, 0, stream>>>(A, Ah, (M * K) / 8, Bq, meta, s, Wt,
                                          K, N, chunksPerGroup, nBlocksN);

  int grid = (M / 256) * (N / 256);
  gemm_kernel<<<grid, 1024, 0, stream>>>(Ah, Wt, bias, C, M, N, K);
}

// Round 18
// 287.998 us; speedup vs baseline: 1.1687x; 1.1687x over previous
//
#include <hip/hip_runtime.h>

typedef _Float16 h16;
typedef __attribute__((ext_vector_type(8))) _Float16 h16x8;
typedef __attribute__((ext_vector_type(4))) float f32x4;
typedef unsigned int u32;

#define BARRIER() __builtin_amdgcn_s_barrier()
#define VMCNT(n)  asm volatile("s_waitcnt vmcnt(" #n ")" ::: "memory")

// ------------- Kernel 1: fused aux = A fp32->fp16  +  2:4 int4 dequant -------
__global__ __launch_bounds__(256) void aux_kernel(const float* __restrict__ A,
    h16* __restrict__ Ah, int total8,
    const int* __restrict__ Bq, const int* __restrict__ meta,
    const float* __restrict__ s, h16* __restrict__ Wt,
    int K, int N, int chunksPerGroup, int nBlocksN) {
  const int bid = blockIdx.x;
  if (bid < 2048) {
    int stride = 2048 * 256;
    for (int i = bid * 256 + threadIdx.x; i < total8; i += stride) {
      const f32x4* p = (const f32x4*)(A + (size_t)i * 8);
      f32x4 v0 = p[0], v1 = p[1];
      h16x8 o;
      o[0] = (h16)v0[0]; o[1] = (h16)v0[1]; o[2] = (h16)v0[2]; o[3] = (h16)v0[3];
      o[4] = (h16)v1[0]; o[5] = (h16)v1[1]; o[6] = (h16)v1[2]; o[7] = (h16)v1[3];
      *(h16x8*)(Ah + (size_t)i * 8) = o;
    }
  } else {
    const int db = bid - 2048;
    const int n = (db % nBlocksN) * 256 + threadIdx.x;   // column of W
    const int chunk = db / nBlocksN;                     // 32 dense k rows
    u32 w0 = (u32)Bq[(size_t)(chunk * 2) * N + n];
    u32 w1 = (u32)Bq[(size_t)(chunk * 2 + 1) * N + n];
    float sc = s[(size_t)(chunk / chunksPerGroup) * N + n];
    h16 out[32];
#pragma unroll
    for (int gi = 0; gi < 8; ++gi) {
      int g = chunk * 8 + gi;
      int mm = meta[(size_t)g * N + n];
      u32 w = (gi < 4) ? w0 : w1;
      int j0 = (2 * gi) & 7;
      float d0 = (float)((int)((w >> (4 * j0)) & 0xFu) - 8) * sc;
      float d1 = (float)((int)((w >> (4 * j0 + 4)) & 0xFu) - 8) * sc;
      u32 enc = (0xED9C84u >> (4 * mm)) & 0xFu;
      int p0 = (int)(enc & 3u), p1 = (int)(enc >> 2);
#pragma unroll
      for (int p = 0; p < 4; ++p) {
        float v = (p == p0) ? d0 : ((p == p1) ? d1 : 0.0f);
        out[gi * 4 + p] = (h16)v;
      }
    }
    h16* dst = Wt + (size_t)n * K + chunk * 32;
    *(h16x8*)(dst + 0)  = *(h16x8*)(out + 0);
    *(h16x8*)(dst + 8)  = *(h16x8*)(out + 8);
    *(h16x8*)(dst + 16) = *(h16x8*)(out + 16);
    *(h16x8*)(dst + 24) = *(h16x8*)(out + 24);
  }
}

// ---------------- Kernel 2: GEMM, R14 loop recipe x 128x64 wave tile --------
// 256x256 block tile, BK=32, 512 threads (8 waves 2Mx4N), per-wave 128x64 out
// (LDS-bytes/FLOP = 0.75x of R14's 64x64 tile: LDS floor ~1155 cyc < MFMA
// ~1242 -> MFMA becomes the critical pipe). R14's proven loop recipe kept
// verbatim: 4-slot 128 KiB LDS rotation, distance-3 prefetch, counted
// vmcnt(8) per tile (4 gloads/thread/tile; tail 8->4->0), ONE barrier/K-tile
// (vs R5's 8 on the same geometry). 2 waves/SIMD -> 256-VGPR budget: acc 128
// + frags 48 + addr ~20, no spill. Reads = clean top-of-iter burst (R17
// lesson: don't interleave reads into the MFMA stream).
// Swizzle: LDS 16B-slot c of row r holds global chunk c ^ ((r>>1)&3);
// read slot = l16 ^ phi(row) -> uniform 2-way bank aliasing (free, m136).
__global__ __launch_bounds__(512, 2) void gemm_kernel(const h16* __restrict__ A,
    const h16* __restrict__ Wt, const float* __restrict__ bias,
    float* __restrict__ C, int M, int N, int K) {
  __shared__ alignas(16) h16 As[4][8192];   // [slot][256 rows x 32] 16 KiB
  __shared__ alignas(16) h16 Bs[4][8192];

  const int nTilesN = N >> 8;
  const int nwg = gridDim.x;
  int bid = blockIdx.x;
  int wg = (bid & 7) * (nwg >> 3) + (bid >> 3);   // XCD swizzle (nwg%8==0)
  int tm = wg / nTilesN, tn = wg - tm * nTilesN;

  const int t = threadIdx.x;
  const int lane = t & 63, w = t >> 6;
  const int wr = w >> 2, wc = w & 3;        // 2M x 4N waves

  // ---- staging: 512 threads cover rows 0..127 directly; rows 128..255 via
  // +128-row offset (phi(r+128)=phi(r): bit 7 doesn't touch row bits 1-2).
  const int srow = t >> 2;                  // 0..127
  const int chunk = (t & 3) ^ ((srow >> 1) & 3);
  const h16* gA_t = A + ((size_t)(tm * 256) + srow) * K + chunk * 8;
  const h16* gB_t = Wt + ((size_t)(tn * 256) + srow) * K + chunk * 8;
  const size_t rowK128 = (size_t)128 * K;
  const int t8 = t * 8;

#define GLOAD(SRC, DST) __builtin_amdgcn_global_load_lds(                      \
    (const __attribute__((address_space(1))) void*)(SRC),                      \
    (__attribute__((address_space(3))) void*)(DST), 16, 0, 0)

#define STAGE(T_) do {                                                         \
    GLOAD(gA_t + (size_t)(T_) * 32, &As[(T_) & 3][t8]);                        \
    GLOAD(gA_t + rowK128 + (size_t)(T_) * 32, &As[(T_) & 3][t8 + 4096]);       \
    GLOAD(gB_t + (size_t)(T_) * 32, &Bs[(T_) & 3][t8]);                        \
    GLOAD(gB_t + rowK128 + (size_t)(T_) * 32, &Bs[(T_) & 3][t8 + 4096]);       \
  } while (0)

  // ---- fragment read offsets: slot = l16 ^ phi(row) ----
  const int ln15 = lane & 15, l16 = lane >> 4;
  const int slA = (l16 ^ ((ln15 >> 1) & 3)) * 8;
  const int aBase = (wr * 128 + ln15) * 32 + slA;   // A rows within [256]
  const int bBase = (wc * 64 + ln15) * 32 + slA;    // B rows within [256]

  f32x4 acc[8][4] = {};
  const int NT = K >> 5;

  // prologue: stage tiles 0,1,2 (12 gloads); retire tile 0 (vmcnt 12->8).
  STAGE(0); STAGE(1); STAGE(2);
  VMCNT(8);
  BARRIER();

  for (int T = 0; T < NT; ++T) {
    const h16* aS = As[T & 3];
    const h16* bS = Bs[T & 3];
    h16x8 af[8], bf[4];
#pragma unroll
    for (int m = 0; m < 8; ++m) af[m] = *(const h16x8*)(aS + aBase + m * 512);
#pragma unroll
    for (int n = 0; n < 4; ++n) bf[n] = *(const h16x8*)(bS + bBase + n * 512);
    if (T + 3 < NT) STAGE(T + 3);   // slot (T+3)&3 = (T-1)&3: read pre-barrier(T-1)
#pragma unroll
    for (int m = 0; m < 8; ++m)
#pragma unroll
      for (int n = 0; n < 4; ++n)
        acc[m][n] = __builtin_amdgcn_mfma_f32_16x16x32_f16(af[m], bf[n], acc[m][n], 0, 0, 0);
    // counted publish of tile T+1; never drain in steady loop.
    if (T + 3 < NT) {
      VMCNT(8);
    } else if (T + 2 < NT) {
      VMCNT(4);
    } else if (T + 1 < NT) {
      VMCNT(0);
    }
    BARRIER();
  }

  // ---- epilogue: col = ln15 (+n*16) from B side, row = l16*4+j (+m*16) ----
  int colBase = tn * 256 + wc * 64 + ln15;
  int rowBase = tm * 256 + wr * 128 + l16 * 4;
#pragma unroll
  for (int n = 0; n < 4; ++n) {
    float bv = bias[colBase + n * 16];
#pragma unroll
    for (int m = 0; m < 8; ++m) {
#pragma unroll
      for (int j = 0; j < 4; ++j) {
        C[(size_t)(rowBase + m * 16 + j) * N + colBase + n * 16] = acc[m][n][j] + bv;
      }
    }
  }
#undef STAGE
#undef GLOAD
}

extern "C" void kernel_launch(void* const* d_in, const int* in_sizes, int n_in,
                              void* d_out, int out_size, void* d_ws, size_t ws_size,
                              hipStream_t stream) {
  const float* A = (const float*)d_in[0];
  const int* Bq = (const int*)d_in[1];
  const int* meta = (const int*)d_in[2];
  const float* s = (const float*)d_in[3];
  const float* bias = (const float*)d_in[4];
  float* C = (float*)d_out;

  const int N = in_sizes[4];
  const int K = (int)(((long long)in_sizes[1] * 16) / N);
  const int M = (int)((long long)in_sizes[0] / K);
  const int sRows = (int)((long long)in_sizes[3] / N);       // K/GS
  const int chunksPerGroup = (K / sRows) / 32;               // GS/32
  const int nBlocksN = N / 256;

  h16* Ah = (h16*)d_ws;                       // M*K f16 = 64 MiB
  h16* Wt = Ah + (size_t)M * K;               // N*K f16 = 32 MiB (W^T, K-major)

  int auxGrid = 2048 + nBlocksN * (K / 32);
  aux_kernel<<<auxGrid, 256, 0, stream>>>(A, Ah, (M * K) / 8, Bq, meta, s, Wt,
                                          K, N, chunksPerGroup, nBlocksN);

  int grid = (M / 256) * (N / 256);
  gemm_kernel<<<grid, 512, 0, stream>>>(Ah, Wt, bias, C, M, N, K);
}

// Round 20
// 282.908 us; speedup vs baseline: 1.1897x; 1.0180x over previous
//
#include <hip/hip_runtime.h>

typedef _Float16 h16;
typedef __attribute__((ext_vector_type(8))) _Float16 h16x8;
typedef __attribute__((ext_vector_type(4))) float f32x4;
typedef unsigned int u32;

#define BARRIER() __builtin_amdgcn_s_barrier()
#define VMCNT(n)  asm volatile("s_waitcnt vmcnt(" #n ")" ::: "memory")

// ------------- Kernel 1: fused aux = A fp32->fp16  +  2:4 int4 dequant -------
__global__ __launch_bounds__(256) void aux_kernel(const float* __restrict__ A,
    h16* __restrict__ Ah, int total8,
    const int* __restrict__ Bq, const int* __restrict__ meta,
    const float* __restrict__ s, h16* __restrict__ Wt,
    int K, int N, int chunksPerGroup, int nBlocksN) {
  const int bid = blockIdx.x;
  if (bid < 2048) {
    int stride = 2048 * 256;
    for (int i = bid * 256 + threadIdx.x; i < total8; i += stride) {
      const f32x4* p = (const f32x4*)(A + (size_t)i * 8);
      f32x4 v0 = p[0], v1 = p[1];
      h16x8 o;
      o[0] = (h16)v0[0]; o[1] = (h16)v0[1]; o[2] = (h16)v0[2]; o[3] = (h16)v0[3];
      o[4] = (h16)v1[0]; o[5] = (h16)v1[1]; o[6] = (h16)v1[2]; o[7] = (h16)v1[3];
      *(h16x8*)(Ah + (size_t)i * 8) = o;
    }
  } else {
    const int db = bid - 2048;
    const int n = (db % nBlocksN) * 256 + threadIdx.x;   // column of W
    const int chunk = db / nBlocksN;                     // 32 dense k rows
    u32 w0 = (u32)Bq[(size_t)(chunk * 2) * N + n];
    u32 w1 = (u32)Bq[(size_t)(chunk * 2 + 1) * N + n];
    float sc = s[(size_t)(chunk / chunksPerGroup) * N + n];
    h16 out[32];
#pragma unroll
    for (int gi = 0; gi < 8; ++gi) {
      int g = chunk * 8 + gi;
      int mm = meta[(size_t)g * N + n];
      u32 w = (gi < 4) ? w0 : w1;
      int j0 = (2 * gi) & 7;
      float d0 = (float)((int)((w >> (4 * j0)) & 0xFu) - 8) * sc;
      float d1 = (float)((int)((w >> (4 * j0 + 4)) & 0xFu) - 8) * sc;
      u32 enc = (0xED9C84u >> (4 * mm)) & 0xFu;
      int p0 = (int)(enc & 3u), p1 = (int)(enc >> 2);
#pragma unroll
      for (int p = 0; p < 4; ++p) {
        float v = (p == p0) ? d0 : ((p == p1) ? d1 : 0.0f);
        out[gi * 4 + p] = (h16)v;
      }
    }
    h16* dst = Wt + (size_t)n * K + chunk * 32;
    *(h16x8*)(dst + 0)  = *(h16x8*)(out + 0);
    *(h16x8*)(dst + 8)  = *(h16x8*)(out + 8);
    *(h16x8*)(dst + 16) = *(h16x8*)(out + 16);
    *(h16x8*)(dst + 24) = *(h16x8*)(out + 24);
  }
}

// ---------------- Kernel 2: GEMM, high-occupancy + counted-vmcnt pipeline ----
// (R14 verbatim — best measured: GEMM 238us, MfmaUtil 55%, total 283us)
// 256x256 tile, BK=32, 1024 threads (16 waves 4Mx4N, 64x64/wave, acc=64
// VGPR), 4 waves/SIMD. 4-slot LDS rotation (128 KiB), prefetch distance 3,
// counted vmcnt(4) per tile (never drain-0 in steady loop; tail 4->2->0).
// One barrier per K-tile. Swizzle: LDS 16B-slot c of row r holds global
// chunk c ^ ((r>>1)&3); read slot = l16 ^ phi(row) -> uniform 2-way (free).
__global__ __launch_bounds__(1024, 4) void gemm_kernel(const h16* __restrict__ A,
    const h16* __restrict__ Wt, const float* __restrict__ bias,
    float* __restrict__ C, int M, int N, int K) {
  __shared__ alignas(16) h16 As[4][8192];
  __shared__ alignas(16) h16 Bs[4][8192];

  const int nTilesN = N >> 8;
  const int nwg = gridDim.x;
  int bid = blockIdx.x;
  int wg = (bid & 7) * (nwg >> 3) + (bid >> 3);   // XCD swizzle (nwg%8==0)
  int tm = wg / nTilesN, tn = wg - tm * nTilesN;

  const int t = threadIdx.x;
  const int lane = t & 63, w = t >> 6;
  const int wr = w >> 2, wc = w & 3;

  // ---- staging: thread t covers LDS 16B-slot t; row=t>>2, dest col c=t&3
  // holds global chunk c ^ phi(row), phi(r) = (r>>1)&3 ----
  const int srow = t >> 2;
  const int chunk = (t & 3) ^ ((srow >> 1) & 3);
  const h16* gA_t = A + ((size_t)(tm * 256) + srow) * K + chunk * 8;
  const h16* gB_t = Wt + ((size_t)(tn * 256) + srow) * K + chunk * 8;
  const int t8 = t * 8;

#define GLOAD(SRC, DST) __builtin_amdgcn_global_load_lds(                      \
    (const __attribute__((address_space(1))) void*)(SRC),                      \
    (__attribute__((address_space(3))) void*)(DST), 16, 0, 0)

#define STAGE(T_) do {                                                         \
    GLOAD(gA_t + (size_t)(T_) * 32, &As[(T_) & 3][t8]);                        \
    GLOAD(gB_t + (size_t)(T_) * 32, &Bs[(T_) & 3][t8]);                        \
  } while (0)

  // ---- fragment read offsets: slot = l16 ^ phi(row) ----
  const int ln15 = lane & 15, l16 = lane >> 4;
  const int slA = (l16 ^ ((ln15 >> 1) & 3)) * 8;
  const int aBase = (wr * 64 + ln15) * 32 + slA;
  const int bBase = (wc * 64 + ln15) * 32 + slA;

  f32x4 acc[4][4] = {};
  const int NT = K >> 5;

  // prologue: stage tiles 0,1,2 (distance 3); retire tile 0; publish.
  STAGE(0); STAGE(1); STAGE(2);
  VMCNT(4);
  BARRIER();

  for (int T = 0; T < NT; ++T) {
    const h16* aS = As[T & 3];
    const h16* bS = Bs[T & 3];
    h16x8 af[4], bf[4];
#pragma unroll
    for (int m = 0; m < 4; ++m) af[m] = *(const h16x8*)(aS + aBase + m * 512);
#pragma unroll
    for (int n = 0; n < 4; ++n) bf[n] = *(const h16x8*)(bS + bBase + n * 512);
    if (T + 3 < NT) STAGE(T + 3);   // slot (T+3)&3 = (T-1)&3: reads done pre-barrier(T-1)
#pragma unroll
    for (int m = 0; m < 4; ++m)
#pragma unroll
      for (int n = 0; n < 4; ++n)
        acc[m][n] = __builtin_amdgcn_mfma_f32_16x16x32_f16(af[m], bf[n], acc[m][n], 0, 0, 0);
    // counted publish: ensure stage(T+1) retired; steady outstanding = 6.
    if (T + 3 < NT) {
      VMCNT(4);
    } else if (T + 2 < NT) {
      VMCNT(2);
    } else if (T + 1 < NT) {
      VMCNT(0);
    }
    BARRIER();
  }

  // ---- epilogue: col = ln15 (+n*16) from B side, row = l16*4+j (+m*16) ----
  int colBase = tn * 256 + wc * 64 + ln15;
  int rowBase = tm * 256 + wr * 64 + l16 * 4;
#pragma unroll
  for (int n = 0; n < 4; ++n) {
    float bv = bias[colBase + n * 16];
#pragma unroll
    for (int m = 0; m < 4; ++m) {
#pragma unroll
      for (int j = 0; j < 4; ++j) {
        C[(size_t)(rowBase + m * 16 + j) * N + colBase + n * 16] = acc[m][n][j] + bv;
      }
    }
  }
#undef STAGE
#undef GLOAD
}

extern "C" void kernel_launch(void* const* d_in, const int* in_sizes, int n_in,
                              void* d_out, int out_size, void* d_ws, size_t ws_size,
                              hipStream_t stream) {
  const float* A = (const float*)d_in[0];
  const int* Bq = (const int*)d_in[1];
  const int* meta = (const int*)d_in[2];
  const float* s = (const float*)d_in[3];
  const float* bias = (const float*)d_in[4];
  float* C = (float*)d_out;

  const int N = in_sizes[4];
  const int K = (int)(((long long)in_sizes[1] * 16) / N);
  const int M = (int)((long long)in_sizes[0] / K);
  const int sRows = (int)((long long)in_sizes[3] / N);       // K/GS
  const int chunksPerGroup = (K / sRows) / 32;               // GS/32
  const int nBlocksN = N / 256;

  h16* Ah = (h16*)d_ws;                       // M*K f16 = 64 MiB
  h16* Wt = Ah + (size_t)M * K;               // N*K f16 = 32 MiB (W^T, K-major)

  int auxGrid = 2048 + nBlocksN * (K / 32);
  aux_kernel<<<auxGrid, 256, 0, stream>>>(A, Ah, (M * K) / 8, Bq, meta, s, Wt,
                                          K, N, chunksPerGroup, nBlocksN);

  int grid = (M / 256) * (N / 256);
  gemm_kernel<<<grid, 1024, 0, stream>>>(Ah, Wt, bias, C, M, N, K);
}